// Round 4
// baseline (949.836 us; speedup 1.0000x reference)
//
#include <hip/hip_runtime.h>
#include <cfloat>
#include <math.h>

#define BT 64
#define CHN 256
#define HH 56
#define WW 56
#define HW 3136          // 56*56
#define NPIX (BT * HW)   // 200704

// ---------------------------------------------------------------------------
// direct global->LDS DMA, 16B per lane; LDS dest = wave-uniform base + lane*16
// ---------------------------------------------------------------------------
__device__ __forceinline__ void dma16(const float* g, float* l) {
    __builtin_amdgcn_global_load_lds(
        (const __attribute__((address_space(1))) void*)g,
        (__attribute__((address_space(3))) void*)l, 16, 0, 0);
}

// ---------------------------------------------------------------------------
// v5: single fused kernel. Correlation volume (81 offsets) + argmax +
// collapsed softmax + IN-LOOP channel-L2 norms (norm_kernel deleted: it was
// pinned at ~830 GB/s / ~247 us across 4 structures; corr already streams
// every byte it needed).
//  - Main loop = v3's exact structure (v4's row-rotation swizzle REVERTED:
//    per-16-lane-phase analysis shows the unpadded layout is already 2-way
//    = free; the rotation created 3-way hotspots, conflicts 2.5e7->4.3e7).
//  - Fused norm: each thread ds_read_b128's back its own DMA slot (lane-
//    linear, conflict-free, +9% LDS traffic) and accumulates f64 squares for
//    its channel-quarter. After the final barrier, dead xs/ps buffers are
//    reused as f64 scratch (exact fit) to reduce 4 quarters -> ivp/ivq.
//  - OOB halo slots stay zero -> masked to ivq=0 (same as before).
//  - f64 sum order differs from the old norm kernel (interleaved quarters):
//    ~1e-16 rel perturbation; argmax keys are f32 bits -> tie-breaks stable.
// ---------------------------------------------------------------------------
__global__ __launch_bounds__(576, 6) void corr_kernel(const float* __restrict__ x,
                                                      float* __restrict__ out) {
    const int tile = blockIdx.x;   // 0..15
    const int b    = blockIdx.y;   // 0..63
    const int offs0 = (tile & 3);
    const int offs1 = (tile >> 2);
    // tile origins {0,16,32,40}: full coverage of 56 with overlap (idempotent writes)
    const int x0 = (offs0 < 3) ? offs0 * 16 : 40;
    const int y0 = (offs1 < 3) ? offs1 * 16 : 40;
    const int tid = threadIdx.x;

    float* outb = out + (size_t)b * 3 * HW;

    if ((b & 7) == 0) {
        // first frame of each segment: x_post == 0 -> r == 0 -> mot = 0, conf = 0
        if (tid < 256) {
            int py = tid >> 4, px = tid & 15;
            int g = (y0 + py) * WW + (x0 + px);
            outb[g] = 0.f; outb[HW + g] = 0.f; outb[2 * HW + g] = 0.f;
        }
        return;
    }

    const int wave = tid >> 6;     // 0..8 == dy row
    const int lane = tid & 63;
    const int ty  = lane >> 2;     // 0..15 tile row
    const int tx4 = lane & 3;      // pixel group: x-local 4*tx4 .. 4*tx4+3

    __shared__ float  xs[2 * 1024];             // [buf][ch][16][16] current tile
    __shared__ float  ps[2 * 2304];             // [buf][ch][24][24] prev halo
    __shared__ double ivq[24 * 25];             // prev inv-norms (halo), 0 if OOB
    __shared__ double ivp[256];                 // current inv-norms
    __shared__ unsigned long long red[256];     // packed argmax, slot = ty + col*16

    const float*  xcur = x + (size_t)b * (CHN * HW);
    const float*  xprv = x + (size_t)(b - 1) * (CHN * HW);

    if (tid < 256) red[tid] = 0ULL;

    // staging descriptors: ps (4ch*24rows*6grp = 576 lanes, float idx = tid*4),
    // xs (4ch*16rows*4grp = 256 lanes, float idx = tid*4)
    int ch_s  = tid / 144;
    int rem_s = tid - ch_s * 144;
    int row_s = rem_s / 6;
    int c4    = rem_s - row_s * 6;
    int gy_s  = y0 - 4 + row_s;
    int gx_s  = x0 - 4 + 4 * c4;
    const bool pv = (gy_s >= 0 && gy_s < HH && gx_s >= 0 && gx_s < WW); // never straddles
    const size_t ps_g = (size_t)ch_s * HW + (pv ? (gy_s * WW + gx_s) : 0);
    size_t xs_g = 0;
    if (tid < 256) {
        int chx = tid >> 6, r2 = tid & 63, sy = r2 >> 2, sx = r2 & 3;
        xs_g = (size_t)chx * HW + (size_t)(y0 + sy) * WW + x0 + 4 * sx;
    }
    // per-wave uniform LDS bases for the DMA (lane*16B appended by HW)
    const int wv = tid >> 6;
    float* const ps_w0 = &ps[wv * 256];             // + buf*2304
    float* const xs_w0 = &xs[wv * 256];             // + buf*1024 (waves 0-3 only)

    // pre-zero cc-invariant OOB halo slots in BOTH buffers (DMA never writes them)
    if (!pv) {
        *(float4*)&ps[tid * 4]        = make_float4(0.f, 0.f, 0.f, 0.f);
        *(float4*)&ps[2304 + tid * 4] = make_float4(0.f, 0.f, 0.f, 0.f);
    }

    // prologue: DMA cc=0 into buffer 0
    if (pv) dma16(xprv + ps_g, ps_w0);
    if (tid < 256) dma16(xcur + xs_g, xs_w0);

    float acc[9][4];
    #pragma unroll
    for (int j = 0; j < 9; ++j)
        #pragma unroll
        for (int t = 0; t < 4; ++t) acc[j][t] = 0.f;

    // fused-norm partial sums (f64), this thread's channel-quarter (ch === ch_s mod 4)
    double sqp0 = 0.0, sqp1 = 0.0, sqp2 = 0.0, sqp3 = 0.0;   // ps slot pixels
    double sqx0 = 0.0, sqx1 = 0.0, sqx2 = 0.0, sqx3 = 0.0;   // xs slot pixels (tid<256)

    __syncthreads();   // vmcnt(0) drain: buffer 0 ready; red init visible

    for (int cc = 0; cc < 64; ++cc) {
        const int cur = cc & 1;
        // issue next stage BEFORE compute: latency hides under LDS reads + FMAs
        if (cc < 63) {
            const size_t cb = (size_t)((cc + 1) * 4) * HW;
            const int nxt = cur ^ 1;
            if (pv) dma16(xprv + cb + ps_g, ps_w0 + nxt * 2304);
            if (tid < 256) dma16(xcur + cb + xs_g, xs_w0 + nxt * 1024);
        }

        // fused norm: read back own DMA slot (lane-linear -> conflict-free)
        {
            float4 rb = *(const float4*)&ps[cur * 2304 + tid * 4];
            sqp0 = fma((double)rb.x, (double)rb.x, sqp0);
            sqp1 = fma((double)rb.y, (double)rb.y, sqp1);
            sqp2 = fma((double)rb.z, (double)rb.z, sqp2);
            sqp3 = fma((double)rb.w, (double)rb.w, sqp3);
        }
        if (tid < 256) {
            float4 rb = *(const float4*)&xs[cur * 1024 + tid * 4];
            sqx0 = fma((double)rb.x, (double)rb.x, sqx0);
            sqx1 = fma((double)rb.y, (double)rb.y, sqx1);
            sqx2 = fma((double)rb.z, (double)rb.z, sqx2);
            sqx3 = fma((double)rb.w, (double)rb.w, sqx3);
        }

        const float* xb = &xs[cur * 1024 + ty * 16 + 4 * tx4];
        const float* pb = &ps[cur * 2304 + (ty + wave) * 24 + 4 * tx4];
        #pragma unroll
        for (int ch = 0; ch < 4; ++ch) {
            float4 xq = *(const float4*)(xb + ch * 256);
            float4 w0 = *(const float4*)(pb + ch * 576);
            float4 w1 = *(const float4*)(pb + ch * 576 + 4);
            float4 w2 = *(const float4*)(pb + ch * 576 + 8);
            float win[12] = { w0.x, w0.y, w0.z, w0.w,
                              w1.x, w1.y, w1.z, w1.w,
                              w2.x, w2.y, w2.z, w2.w };
            #pragma unroll
            for (int dx = 0; dx < 9; ++dx) {
                acc[dx][0] = fmaf(xq.x, win[dx + 0], acc[dx][0]);
                acc[dx][1] = fmaf(xq.y, win[dx + 1], acc[dx][1]);
                acc[dx][2] = fmaf(xq.z, win[dx + 2], acc[dx][2]);
                acc[dx][3] = fmaf(xq.w, win[dx + 3], acc[dx][3]);
            }
        }
        // single barrier per cc: compiler emits vmcnt(0) here, draining the
        // next-stage DMA (issued one full compute phase ago) + releases cur buf
        __syncthreads();
    }

    // ---- fused norms: reduce the 4 channel-quarter partials per pixel ----
    // Both staging buffers are dead after the final barrier; reuse as f64
    // scratch (exact fit: ps 2*2304 floats = 2304 doubles, xs = 1024 doubles).
    double* psq = (double*)ps;
    double* xsq = (double*)xs;
    psq[tid * 4 + 0] = sqp0;
    psq[tid * 4 + 1] = sqp1;
    psq[tid * 4 + 2] = sqp2;
    psq[tid * 4 + 3] = sqp3;
    if (tid < 256) {
        xsq[tid * 4 + 0] = sqx0;
        xsq[tid * 4 + 1] = sqx1;
        xsq[tid * 4 + 2] = sqx2;
        xsq[tid * 4 + 3] = sqx3;
    }
    __syncthreads();
    {
        // halo pixel (hr, hc): partials live at slot (q*144 + hr*6 + hc/4), elem hc&3
        int hr = tid / 24, hc = tid - hr * 24;
        int gy = y0 - 4 + hr, gx = x0 - 4 + hc;
        int sl = (hr * 6 + (hc >> 2)) * 4 + (hc & 3);
        double s = psq[sl] + psq[576 + sl] + psq[1152 + sl] + psq[1728 + sl];
        ivq[hr * 25 + hc] = (gy >= 0 && gy < HH && gx >= 0 && gx < WW)
                          ? 1.0 / fmax(sqrt(s), 1e-12) : 0.0;
    }
    if (tid < 256) {
        int r = tid >> 4, c = tid & 15;
        int sl = (r * 4 + (c >> 2)) * 4 + (c & 3);
        double s = xsq[sl] + xsq[256 + sl] + xsq[512 + sl] + xsq[768 + sl];
        ivp[tid] = 1.0 / fmax(sqrt(s), 1e-12);
    }
    __syncthreads();

    // epilogue: local argmax over this wave's 9 offsets, packed-u64 merge
    const int px0 = ty * 16 + 4 * tx4;
    double ip[4];
    #pragma unroll
    for (int t = 0; t < 4; ++t) ip[t] = ivp[px0 + t];
    unsigned long long best[4] = { 0ULL, 0ULL, 0ULL, 0ULL };
    #pragma unroll
    for (int dx = 0; dx < 9; ++dx) {
        #pragma unroll
        for (int t = 0; t < 4; ++t) {
            double qv = ivq[(ty + wave) * 25 + 4 * tx4 + t + dx];
            float rv = (float)((double)acc[dx][t] * ip[t] * qv);
            unsigned int bits = __float_as_uint(rv);
            unsigned int key = (bits & 0x80000000u) ? ~bits : (bits | 0x80000000u);
            unsigned long long pk =
                ((unsigned long long)key << 32) | (unsigned int)(80 - (wave * 9 + dx));
            if (pk > best[t]) best[t] = pk;   // ascending dx + strict > == first-max
        }
    }
    #pragma unroll
    for (int t = 0; t < 4; ++t)
        atomicMax(&red[ty + ((4 * tx4 + t) << 4)], best[t]);   // bank-spread layout
    __syncthreads();

    if (tid < 256) {
        unsigned long long pk = red[(tid >> 4) + ((tid & 15) << 4)];
        int o = 80 - (int)(pk & 0xffffffffu);
        unsigned int key  = (unsigned int)(pk >> 32);
        unsigned int bits = (key & 0x80000000u) ? (key ^ 0x80000000u) : ~key;
        float v = __uint_as_float(bits);
        float h_idx = (float)(o / 9) - 4.f;
        float v_idx = (float)(o - (o / 9) * 9) - 4.f;
        // gaussian(sigma=0.1) zeroes all non-argmax cells below fp32 resolution:
        // h_cord = h_idx * R/(R+1e-12), R = BETA * r_max
        float R2  = 10.f * v;
        float pc2 = R2 / (R2 + 1e-12f);
        int py = tid >> 4, pxl = tid & 15;
        int g = (y0 + py) * WW + (x0 + pxl);
        outb[g]          = h_idx * pc2;
        outb[HW + g]     = v_idx * pc2;
        outb[2 * HW + g] = v;
    }
}

extern "C" void kernel_launch(void* const* d_in, const int* in_sizes, int n_in,
                              void* d_out, int out_size, void* d_ws, size_t ws_size,
                              hipStream_t stream) {
    const float* x = (const float*)d_in[0];
    float* out = (float*)d_out;
    (void)d_ws; (void)ws_size;   // norm kernel + invn workspace eliminated (fused)

    hipLaunchKernelGGL(corr_kernel, dim3(16, 64), dim3(576), 0, stream,
                       x, out);
}

// Round 5
// 858.604 us; speedup vs baseline: 1.1063x; 1.1063x over previous
//
#include <hip/hip_runtime.h>
#include <cfloat>
#include <math.h>

#define BT 64
#define CHN 256
#define HH 56
#define WW 56
#define HW 3136          // 56*56
#define NPIX (BT * HW)   // 200704

// ---------------------------------------------------------------------------
// direct global->LDS DMA, 16B per lane; LDS dest = wave-uniform base + lane*16
// ---------------------------------------------------------------------------
__device__ __forceinline__ void dma16(const float* g, float* l) {
    __builtin_amdgcn_global_load_lds(
        (const __attribute__((address_space(1))) void*)g,
        (__attribute__((address_space(3))) void*)l, 16, 0, 0);
}

// ---------------------------------------------------------------------------
// v6: single fused kernel, norms accumulated FROM REGISTERS THE FMA LOOP
// ALREADY LOADS (v5's extra LDS readback caused bank-collision with the
// in-flight DMA writes: conflicts 2.5e7 -> 1.39e8; reverted).
//  - Main loop = v3's exact structure (proven 322 us), untouched.
//  - ivp: every wave's xq covers the full 16x16 tile each (cc,ch); wave 0
//    accumulates xq^2 into pp[4] (f64). Zero extra LDS reads.
//  - ivq: halo row R=ty+wave. Rows 0-7 are read only by wave r's ty==0
//    lanes; rows 8-23 by wave 8. Cols 0-15 from w0 (all tx4), cols 16-23
//    from w2 (tx4 in {2,3}). Each (row,col) covered exactly once ->
//    q0[4]/q2[4] f64 accumulators, zero extra LDS reads.
//  - Post-loop: owners write ivq/ivp directly (OOB-masked), one barrier,
//    then the unchanged argmax epilogue.
//  - __launch_bounds__(576,3): v2/v5 both regressed with huge WRITE_SIZE
//    (scratch spill) after adding ~8-16 VGPRs under (576,6) -> suspected
//    VGPR cap ~146. (576,3) lifts the cap for the +24 f64 accumulator regs.
//  - f64 sum order differs from the old norm kernel: proven harmless (v5
//    changed order completely, absmax identical 5.459392e-22).
// ---------------------------------------------------------------------------
__global__ __launch_bounds__(576, 3) void corr_kernel(const float* __restrict__ x,
                                                      float* __restrict__ out) {
    const int tile = blockIdx.x;   // 0..15
    const int b    = blockIdx.y;   // 0..63
    const int offs0 = (tile & 3);
    const int offs1 = (tile >> 2);
    // tile origins {0,16,32,40}: full coverage of 56 with overlap (idempotent writes)
    const int x0 = (offs0 < 3) ? offs0 * 16 : 40;
    const int y0 = (offs1 < 3) ? offs1 * 16 : 40;
    const int tid = threadIdx.x;

    float* outb = out + (size_t)b * 3 * HW;

    if ((b & 7) == 0) {
        // first frame of each segment: x_post == 0 -> r == 0 -> mot = 0, conf = 0
        if (tid < 256) {
            int py = tid >> 4, px = tid & 15;
            int g = (y0 + py) * WW + (x0 + px);
            outb[g] = 0.f; outb[HW + g] = 0.f; outb[2 * HW + g] = 0.f;
        }
        return;
    }

    const int wave = tid >> 6;     // 0..8 == dy row
    const int lane = tid & 63;
    const int ty  = lane >> 2;     // 0..15 tile row
    const int tx4 = lane & 3;      // pixel group: x-local 4*tx4 .. 4*tx4+3

    __shared__ float  xs[2 * 1024];             // [buf][ch][16][16] current tile
    __shared__ float  ps[2 * 2304];             // [buf][ch][24][24] prev halo
    __shared__ double ivq[24 * 25];             // prev inv-norms (halo), 0 if OOB
    __shared__ double ivp[256];                 // current inv-norms
    __shared__ unsigned long long red[256];     // packed argmax, slot = ty + col*16

    const float*  xcur = x + (size_t)b * (CHN * HW);
    const float*  xprv = x + (size_t)(b - 1) * (CHN * HW);

    if (tid < 256) red[tid] = 0ULL;

    // staging descriptors: ps (4ch*24rows*6grp = 576 lanes, float idx = tid*4),
    // xs (4ch*16rows*4grp = 256 lanes, float idx = tid*4)
    int ch_s  = tid / 144;
    int rem_s = tid - ch_s * 144;
    int row_s = rem_s / 6;
    int c4    = rem_s - row_s * 6;
    int gy_s  = y0 - 4 + row_s;
    int gx_s  = x0 - 4 + 4 * c4;
    const bool pv = (gy_s >= 0 && gy_s < HH && gx_s >= 0 && gx_s < WW); // never straddles
    const size_t ps_g = (size_t)ch_s * HW + (pv ? (gy_s * WW + gx_s) : 0);
    size_t xs_g = 0;
    if (tid < 256) {
        int chx = tid >> 6, r2 = tid & 63, sy = r2 >> 2, sx = r2 & 3;
        xs_g = (size_t)chx * HW + (size_t)(y0 + sy) * WW + x0 + 4 * sx;
    }
    // per-wave uniform LDS bases for the DMA (lane*16B appended by HW)
    const int wv = tid >> 6;
    float* const ps_w0 = &ps[wv * 256];             // + buf*2304
    float* const xs_w0 = &xs[wv * 256];             // + buf*1024 (waves 0-3 only)

    // pre-zero cc-invariant OOB halo slots in BOTH buffers (DMA never writes them)
    if (!pv) {
        *(float4*)&ps[tid * 4]        = make_float4(0.f, 0.f, 0.f, 0.f);
        *(float4*)&ps[2304 + tid * 4] = make_float4(0.f, 0.f, 0.f, 0.f);
    }

    // prologue: DMA cc=0 into buffer 0
    if (pv) dma16(xprv + ps_g, ps_w0);
    if (tid < 256) dma16(xcur + xs_g, xs_w0);

    float acc[9][4];
    #pragma unroll
    for (int j = 0; j < 9; ++j)
        #pragma unroll
        for (int t = 0; t < 4; ++t) acc[j][t] = 0.f;

    // fused-norm f64 accumulators (from values the FMA loop already loads)
    double q0[4] = {0.0, 0.0, 0.0, 0.0};   // ivq cols 4*tx4..+3   (qown lanes)
    double q2[4] = {0.0, 0.0, 0.0, 0.0};   // ivq cols 16..23      (qown, tx4>=2)
    double pp[4] = {0.0, 0.0, 0.0, 0.0};   // ivp pixels           (wave 0)
    const bool qown = (ty == 0) || (wave == 8);

    __syncthreads();   // vmcnt(0) drain: buffer 0 ready; red init visible

    for (int cc = 0; cc < 64; ++cc) {
        const int cur = cc & 1;
        // issue next stage BEFORE compute: latency hides under LDS reads + FMAs
        if (cc < 63) {
            const size_t cb = (size_t)((cc + 1) * 4) * HW;
            const int nxt = cur ^ 1;
            if (pv) dma16(xprv + cb + ps_g, ps_w0 + nxt * 2304);
            if (tid < 256) dma16(xcur + cb + xs_g, xs_w0 + nxt * 1024);
        }

        const float* xb = &xs[cur * 1024 + ty * 16 + 4 * tx4];
        const float* pb = &ps[cur * 2304 + (ty + wave) * 24 + 4 * tx4];
        #pragma unroll
        for (int ch = 0; ch < 4; ++ch) {
            float4 xq = *(const float4*)(xb + ch * 256);
            float4 w0 = *(const float4*)(pb + ch * 576);
            float4 w1 = *(const float4*)(pb + ch * 576 + 4);
            float4 w2 = *(const float4*)(pb + ch * 576 + 8);

            // fused norms: squares of already-loaded registers
            if (wave == 0) {                       // wave-uniform: waves 1-8 skip
                pp[0] = fma((double)xq.x, (double)xq.x, pp[0]);
                pp[1] = fma((double)xq.y, (double)xq.y, pp[1]);
                pp[2] = fma((double)xq.z, (double)xq.z, pp[2]);
                pp[3] = fma((double)xq.w, (double)xq.w, pp[3]);
            }
            if (qown) {                            // masked for waves 0-7 (ty==0)
                q0[0] = fma((double)w0.x, (double)w0.x, q0[0]);
                q0[1] = fma((double)w0.y, (double)w0.y, q0[1]);
                q0[2] = fma((double)w0.z, (double)w0.z, q0[2]);
                q0[3] = fma((double)w0.w, (double)w0.w, q0[3]);
                q2[0] = fma((double)w2.x, (double)w2.x, q2[0]);   // used iff tx4>=2
                q2[1] = fma((double)w2.y, (double)w2.y, q2[1]);
                q2[2] = fma((double)w2.z, (double)w2.z, q2[2]);
                q2[3] = fma((double)w2.w, (double)w2.w, q2[3]);
            }

            float win[12] = { w0.x, w0.y, w0.z, w0.w,
                              w1.x, w1.y, w1.z, w1.w,
                              w2.x, w2.y, w2.z, w2.w };
            #pragma unroll
            for (int dx = 0; dx < 9; ++dx) {
                acc[dx][0] = fmaf(xq.x, win[dx + 0], acc[dx][0]);
                acc[dx][1] = fmaf(xq.y, win[dx + 1], acc[dx][1]);
                acc[dx][2] = fmaf(xq.z, win[dx + 2], acc[dx][2]);
                acc[dx][3] = fmaf(xq.w, win[dx + 3], acc[dx][3]);
            }
        }
        // single barrier per cc: compiler emits vmcnt(0) here, draining the
        // next-stage DMA (issued one full compute phase ago) + releases cur buf
        __syncthreads();
    }

    // ---- write inv-norms directly from owner lanes (no scratch needed) ----
    if (wave == 0) {
        #pragma unroll
        for (int t = 0; t < 4; ++t)
            ivp[ty * 16 + 4 * tx4 + t] = 1.0 / fmax(sqrt(pp[t]), 1e-12);
    }
    if (qown) {
        const int R  = ty + wave;          // waves 0-7: row=wave; wave 8: 8..23
        const int gy = y0 - 4 + R;
        const bool ry = (gy >= 0 && gy < HH);
        #pragma unroll
        for (int t = 0; t < 4; ++t) {
            int c = 4 * tx4 + t, gx = x0 - 4 + c;
            ivq[R * 25 + c] = (ry && gx >= 0 && gx < WW)
                            ? 1.0 / fmax(sqrt(q0[t]), 1e-12) : 0.0;
        }
        if (tx4 >= 2) {
            #pragma unroll
            for (int t = 0; t < 4; ++t) {
                int c = 16 + 4 * (tx4 - 2) + t, gx = x0 - 4 + c;
                ivq[R * 25 + c] = (ry && gx >= 0 && gx < WW)
                                ? 1.0 / fmax(sqrt(q2[t]), 1e-12) : 0.0;
            }
        }
    }
    __syncthreads();

    // epilogue: local argmax over this wave's 9 offsets, packed-u64 merge
    const int px0 = ty * 16 + 4 * tx4;
    double ip[4];
    #pragma unroll
    for (int t = 0; t < 4; ++t) ip[t] = ivp[px0 + t];
    unsigned long long best[4] = { 0ULL, 0ULL, 0ULL, 0ULL };
    #pragma unroll
    for (int dx = 0; dx < 9; ++dx) {
        #pragma unroll
        for (int t = 0; t < 4; ++t) {
            double qv = ivq[(ty + wave) * 25 + 4 * tx4 + t + dx];
            float rv = (float)((double)acc[dx][t] * ip[t] * qv);
            unsigned int bits = __float_as_uint(rv);
            unsigned int key = (bits & 0x80000000u) ? ~bits : (bits | 0x80000000u);
            unsigned long long pk =
                ((unsigned long long)key << 32) | (unsigned int)(80 - (wave * 9 + dx));
            if (pk > best[t]) best[t] = pk;   // ascending dx + strict > == first-max
        }
    }
    #pragma unroll
    for (int t = 0; t < 4; ++t)
        atomicMax(&red[ty + ((4 * tx4 + t) << 4)], best[t]);   // bank-spread layout
    __syncthreads();

    if (tid < 256) {
        unsigned long long pk = red[(tid >> 4) + ((tid & 15) << 4)];
        int o = 80 - (int)(pk & 0xffffffffu);
        unsigned int key  = (unsigned int)(pk >> 32);
        unsigned int bits = (key & 0x80000000u) ? (key ^ 0x80000000u) : ~key;
        float v = __uint_as_float(bits);
        float h_idx = (float)(o / 9) - 4.f;
        float v_idx = (float)(o - (o / 9) * 9) - 4.f;
        // gaussian(sigma=0.1) zeroes all non-argmax cells below fp32 resolution:
        // h_cord = h_idx * R/(R+1e-12), R = BETA * r_max
        float R2  = 10.f * v;
        float pc2 = R2 / (R2 + 1e-12f);
        int py = tid >> 4, pxl = tid & 15;
        int g = (y0 + py) * WW + (x0 + pxl);
        outb[g]          = h_idx * pc2;
        outb[HW + g]     = v_idx * pc2;
        outb[2 * HW + g] = v;
    }
}

extern "C" void kernel_launch(void* const* d_in, const int* in_sizes, int n_in,
                              void* d_out, int out_size, void* d_ws, size_t ws_size,
                              hipStream_t stream) {
    const float* x = (const float*)d_in[0];
    float* out = (float*)d_out;
    (void)d_ws; (void)ws_size;   // fused: no norm kernel, no invn workspace

    hipLaunchKernelGGL(corr_kernel, dim3(16, 64), dim3(576), 0, stream,
                       x, out);
}

// Round 6
// 585.795 us; speedup vs baseline: 1.6214x; 1.4657x over previous
//
#include <hip/hip_runtime.h>
#include <cfloat>
#include <math.h>

#define BT 64
#define CHN 256
#define HH 56
#define WW 56
#define HW 3136          // 56*56
#define NPIX (BT * HW)   // 200704

// ---------------------------------------------------------------------------
// Kernel A (v7): per-pixel channel sum-of-squares (f64) via 1KB/wave reads.
// Prior norm variants were pinned at ~830 GB/s: every structure read only
// 256B contiguous per wave-instruction (64px x 4B) at 12.5KB channel stride.
// Here thread t owns float4 pixel-group t (784 groups), so lanes 0..63 read
// 64 CONSECUTIVE float4s = 1KB/wave/instr. Block = (32-channel chunk, b);
// grid 8x64 = 512 blocks = 2/CU. Chunk partials merge with native f64
// global atomicAdd (f64 sum order empirically irrelevant: v0/v4/v5/v6 all
// permuted it, absmax bit-identical). invn is NOT computed here; corr does
// 1/max(sqrt(ss),1e-12) at its staging loads.
// ---------------------------------------------------------------------------
__global__ __launch_bounds__(784) void sumsq_kernel(const float* __restrict__ x,
                                                    double* __restrict__ sq) {
    const int g = threadIdx.x;       // float4 pixel-group 0..783
    const int q = blockIdx.x;        // channel chunk (32 channels)
    const int b = blockIdx.y;
    const float* xb = x + (size_t)b * (CHN * HW) + (size_t)(q * 32) * HW + 4 * g;
    double s0 = 0.0, s1 = 0.0, s2 = 0.0, s3 = 0.0;
    #pragma unroll 8
    for (int c = 0; c < 32; ++c) {
        float4 v = *(const float4*)(xb + (size_t)c * HW);
        s0 = fma((double)v.x, (double)v.x, s0);
        s1 = fma((double)v.y, (double)v.y, s1);
        s2 = fma((double)v.z, (double)v.z, s2);
        s3 = fma((double)v.w, (double)v.w, s3);
    }
    double* d = sq + (size_t)b * HW + 4 * g;
    atomicAdd(d + 0, s0);
    atomicAdd(d + 1, s1);
    atomicAdd(d + 2, s2);
    atomicAdd(d + 3, s3);
}

// ---------------------------------------------------------------------------
// direct global->LDS DMA, 16B per lane; LDS dest = wave-uniform base + lane*16
// ---------------------------------------------------------------------------
__device__ __forceinline__ void dma16(const float* g, float* l) {
    __builtin_amdgcn_global_load_lds(
        (const __attribute__((address_space(1))) void*)g,
        (__attribute__((address_space(3))) void*)l, 16, 0, 0);
}

// ---------------------------------------------------------------------------
// Kernel B: correlation volume (81 offsets) + argmax + collapsed softmax.
// EXACT v3 structure (proven 322 us; v4 swizzle and v5/v6 norm fusion both
// regressed and are reverted). Only change vs v3: inputs are raw sum-of-
// squares (f64) instead of precomputed inv-norms; the staging loads apply
// 1/max(sqrt(ss),1e-12) (once per staged value per block - noise).
// ---------------------------------------------------------------------------
__global__ __launch_bounds__(576, 6) void corr_kernel(const float* __restrict__ x,
                                                      const double* __restrict__ sq,
                                                      float* __restrict__ out) {
    const int tile = blockIdx.x;   // 0..15
    const int b    = blockIdx.y;   // 0..63
    const int offs0 = (tile & 3);
    const int offs1 = (tile >> 2);
    // tile origins {0,16,32,40}: full coverage of 56 with overlap (idempotent writes)
    const int x0 = (offs0 < 3) ? offs0 * 16 : 40;
    const int y0 = (offs1 < 3) ? offs1 * 16 : 40;
    const int tid = threadIdx.x;

    float* outb = out + (size_t)b * 3 * HW;

    if ((b & 7) == 0) {
        // first frame of each segment: x_post == 0 -> r == 0 -> mot = 0, conf = 0
        if (tid < 256) {
            int py = tid >> 4, px = tid & 15;
            int g = (y0 + py) * WW + (x0 + px);
            outb[g] = 0.f; outb[HW + g] = 0.f; outb[2 * HW + g] = 0.f;
        }
        return;
    }

    const int wave = tid >> 6;     // 0..8 == dy row
    const int lane = tid & 63;
    const int ty  = lane >> 2;     // 0..15 tile row
    const int tx4 = lane & 3;      // pixel group: x-local 4*tx4 .. 4*tx4+3

    __shared__ float  xs[2 * 1024];             // [buf][ch][16][16] current tile
    __shared__ float  ps[2 * 2304];             // [buf][ch][24][24] prev halo
    __shared__ double ivq[24 * 25];             // prev inv-norms (halo), 0 if OOB
    __shared__ double ivp[256];                 // current inv-norms
    __shared__ unsigned long long red[256];     // packed argmax, slot = ty + col*16

    const float*  xcur   = x  + (size_t)b * (CHN * HW);
    const float*  xprv   = x  + (size_t)(b - 1) * (CHN * HW);
    const double* sq_cur = sq + (size_t)b * HW;
    const double* sq_prv = sq + (size_t)(b - 1) * HW;

    // stage inverse norms + init reduction slots (576 = 24*24 exactly)
    {
        int row = tid / 24, col = tid - row * 24;
        int gy = y0 - 4 + row, gx = x0 - 4 + col;
        double v = 0.0;
        if (gy >= 0 && gy < HH && gx >= 0 && gx < WW)
            v = 1.0 / fmax(sqrt(sq_prv[gy * WW + gx]), 1e-12);
        ivq[row * 25 + col] = v;
    }
    if (tid < 256) {
        ivp[tid] = 1.0 / fmax(sqrt(sq_cur[(y0 + (tid >> 4)) * WW + x0 + (tid & 15)]), 1e-12);
        red[tid] = 0ULL;
    }

    // staging descriptors: ps (4ch*24rows*6grp = 576 lanes, float idx = tid*4),
    // xs (4ch*16rows*4grp = 256 lanes, float idx = tid*4)
    int ch_s  = tid / 144;
    int rem_s = tid - ch_s * 144;
    int row_s = rem_s / 6;
    int c4    = rem_s - row_s * 6;
    int gy_s  = y0 - 4 + row_s;
    int gx_s  = x0 - 4 + 4 * c4;
    const bool pv = (gy_s >= 0 && gy_s < HH && gx_s >= 0 && gx_s < WW); // never straddles
    const size_t ps_g = (size_t)ch_s * HW + (pv ? (gy_s * WW + gx_s) : 0);
    size_t xs_g = 0;
    if (tid < 256) {
        int chx = tid >> 6, r2 = tid & 63, sy = r2 >> 2, sx = r2 & 3;
        xs_g = (size_t)chx * HW + (size_t)(y0 + sy) * WW + x0 + 4 * sx;
    }
    // per-wave uniform LDS bases for the DMA (lane*16B appended by HW)
    const int wv = tid >> 6;
    float* const ps_w0 = &ps[wv * 256];             // + buf*2304
    float* const xs_w0 = &xs[wv * 256];             // + buf*1024 (waves 0-3 only)

    // pre-zero cc-invariant OOB halo slots in BOTH buffers (DMA never writes them)
    if (!pv) {
        *(float4*)&ps[tid * 4]        = make_float4(0.f, 0.f, 0.f, 0.f);
        *(float4*)&ps[2304 + tid * 4] = make_float4(0.f, 0.f, 0.f, 0.f);
    }

    // prologue: DMA cc=0 into buffer 0
    if (pv) dma16(xprv + ps_g, ps_w0);
    if (tid < 256) dma16(xcur + xs_g, xs_w0);

    float acc[9][4];
    #pragma unroll
    for (int j = 0; j < 9; ++j)
        #pragma unroll
        for (int t = 0; t < 4; ++t) acc[j][t] = 0.f;

    __syncthreads();   // vmcnt(0) drain: buffer 0 ready; ivq/ivp/red visible

    for (int cc = 0; cc < 64; ++cc) {
        const int cur = cc & 1;
        // issue next stage BEFORE compute: latency hides under LDS reads + FMAs
        if (cc < 63) {
            const size_t cb = (size_t)((cc + 1) * 4) * HW;
            const int nxt = cur ^ 1;
            if (pv) dma16(xprv + cb + ps_g, ps_w0 + nxt * 2304);
            if (tid < 256) dma16(xcur + cb + xs_g, xs_w0 + nxt * 1024);
        }

        const float* xb = &xs[cur * 1024 + ty * 16 + 4 * tx4];
        const float* pb = &ps[cur * 2304 + (ty + wave) * 24 + 4 * tx4];
        #pragma unroll
        for (int ch = 0; ch < 4; ++ch) {
            float4 xq = *(const float4*)(xb + ch * 256);
            float4 w0 = *(const float4*)(pb + ch * 576);
            float4 w1 = *(const float4*)(pb + ch * 576 + 4);
            float4 w2 = *(const float4*)(pb + ch * 576 + 8);
            float win[12] = { w0.x, w0.y, w0.z, w0.w,
                              w1.x, w1.y, w1.z, w1.w,
                              w2.x, w2.y, w2.z, w2.w };
            #pragma unroll
            for (int dx = 0; dx < 9; ++dx) {
                acc[dx][0] = fmaf(xq.x, win[dx + 0], acc[dx][0]);
                acc[dx][1] = fmaf(xq.y, win[dx + 1], acc[dx][1]);
                acc[dx][2] = fmaf(xq.z, win[dx + 2], acc[dx][2]);
                acc[dx][3] = fmaf(xq.w, win[dx + 3], acc[dx][3]);
            }
        }
        // single barrier per cc: compiler emits vmcnt(0) here, draining the
        // next-stage DMA (issued one full compute phase ago) + releases cur buf
        __syncthreads();
    }

    // epilogue: local argmax over this wave's 9 offsets, packed-u64 merge
    const int px0 = ty * 16 + 4 * tx4;
    double ip[4];
    #pragma unroll
    for (int t = 0; t < 4; ++t) ip[t] = ivp[px0 + t];
    unsigned long long best[4] = { 0ULL, 0ULL, 0ULL, 0ULL };
    #pragma unroll
    for (int dx = 0; dx < 9; ++dx) {
        #pragma unroll
        for (int t = 0; t < 4; ++t) {
            double qv = ivq[(ty + wave) * 25 + 4 * tx4 + t + dx];
            float rv = (float)((double)acc[dx][t] * ip[t] * qv);
            unsigned int bits = __float_as_uint(rv);
            unsigned int key = (bits & 0x80000000u) ? ~bits : (bits | 0x80000000u);
            unsigned long long pk =
                ((unsigned long long)key << 32) | (unsigned int)(80 - (wave * 9 + dx));
            if (pk > best[t]) best[t] = pk;   // ascending dx + strict > == first-max
        }
    }
    #pragma unroll
    for (int t = 0; t < 4; ++t)
        atomicMax(&red[ty + ((4 * tx4 + t) << 4)], best[t]);   // bank-spread layout
    __syncthreads();

    if (tid < 256) {
        unsigned long long pk = red[(tid >> 4) + ((tid & 15) << 4)];
        int o = 80 - (int)(pk & 0xffffffffu);
        unsigned int key  = (unsigned int)(pk >> 32);
        unsigned int bits = (key & 0x80000000u) ? (key ^ 0x80000000u) : ~key;
        float v = __uint_as_float(bits);
        float h_idx = (float)(o / 9) - 4.f;
        float v_idx = (float)(o - (o / 9) * 9) - 4.f;
        // gaussian(sigma=0.1) zeroes all non-argmax cells below fp32 resolution:
        // h_cord = h_idx * R/(R+1e-12), R = BETA * r_max
        float R2  = 10.f * v;
        float pc2 = R2 / (R2 + 1e-12f);
        int py = tid >> 4, pxl = tid & 15;
        int g = (y0 + py) * WW + (x0 + pxl);
        outb[g]          = h_idx * pc2;
        outb[HW + g]     = v_idx * pc2;
        outb[2 * HW + g] = v;
    }
}

extern "C" void kernel_launch(void* const* d_in, const int* in_sizes, int n_in,
                              void* d_out, int out_size, void* d_ws, size_t ws_size,
                              hipStream_t stream) {
    const float* x = (const float*)d_in[0];
    float* out = (float*)d_out;
    double* sq = (double*)d_ws;   // 200704 doubles = 1.6 MB sum-of-squares

    hipMemsetAsync(d_ws, 0, (size_t)NPIX * sizeof(double), stream);
    hipLaunchKernelGGL(sumsq_kernel, dim3(8, 64), dim3(784), 0, stream,
                       x, sq);
    hipLaunchKernelGGL(corr_kernel, dim3(16, 64), dim3(576), 0, stream,
                       x, sq, out);
}